// Round 8
// baseline (406.516 us; speedup 1.0000x reference)
//
#include <hip/hip_runtime.h>
#include <hip/hip_bf16.h>

// Problem constants
#define NB   256
#define NC   4096
#define NG   512
#define NH   128
#define NELEM (NB*NC)            // 1048576
#define LDX  66                  // row stride of x_with_meta in floats
#define NEGV (-1000000000.0f)
#define TILES 4                  // 128-row tiles per block
#define TILE_ROWS 128
#define GRID_MLP (NELEM/(TILES*TILE_ROWS))   // 2048

typedef __attribute__((ext_vector_type(8))) short short8;
typedef __attribute__((ext_vector_type(4))) float f32x4;

// truncating f32->bf16 pair pack (threshold makes RNE unnecessary on hot path)
__device__ __forceinline__ unsigned pack2(float x, float y) {
    return (__float_as_uint(y) & 0xFFFF0000u) | (__float_as_uint(x) >> 16);
}
__device__ __forceinline__ unsigned short f2bf(float f) {   // RNE, off hot path
    unsigned u = __float_as_uint(f);
    return (unsigned short)((u + 0x7FFFu + ((u >> 16) & 1u)) >> 16);
}
__device__ __forceinline__ unsigned char f2fp8(float f) {   // e4m3, off hot path
    return (unsigned char)((unsigned)__builtin_amdgcn_cvt_pk_fp8_f32(f, 0.f, 0, false) & 0xFFu);
}
__device__ __forceinline__ unsigned encf(float f) {         // order-preserving f32->u32
    unsigned u = __float_as_uint(f);
    return (u & 0x80000000u) ? ~u : (u | 0x80000000u);
}
__device__ __forceinline__ float decf(unsigned u) {
    unsigned v = (u & 0x80000000u) ? (u ^ 0x80000000u) : ~u;
    return __uint_as_float(v);
}
__device__ __forceinline__ f32x4 mfma_bf16(short8 a, short8 b, f32x4 c) {
    return __builtin_amdgcn_mfma_f32_16x16x32_bf16(a, b, c, 0, 0, 0);
}
__device__ __forceinline__ f32x4 mfma_fp8(long a, long b, f32x4 c) {
    return __builtin_amdgcn_mfma_f32_16x16x32_fp8_fp8(a, b, c, 0, 0, 0);
}

// ---- kernel 0: weight prep --------------------------------------------------
// W0T:  bf16 [h=128][8 units of 8], unit swizzled u' = u ^ (h&7)
// W1f8s: fp8 [j=128][16 units of 8], unit swizzled u' = u ^ (j&7)
__global__ void k_prep(const float* __restrict__ W0, const float* __restrict__ W1,
                       unsigned short* __restrict__ W0T, unsigned char* __restrict__ W1f8s) {
    int i = blockIdx.x * 256 + threadIdx.x;
    if (i < 8192) {                       // elem (h, c): W0T holds W0[c][h]
        int h = i >> 6, c = i & 63;
        W0T[h * 64 + ((c >> 3) ^ (h & 7)) * 8 + (c & 7)] = f2bf(W0[c * NH + h]);
    } else if (i < 24576) {               // elem (j, c): W1f8s holds W1[c][j]
        int i2 = i - 8192;
        int j = i2 >> 7, c = i2 & 127;
        W1f8s[(j * 16 + ((c >> 3) ^ (j & 7))) * 8 + (c & 7)] = f2fp8(W1[c * NH + j]);
    }
}

// ---- kernel 1: fused MLP (NO atomics) ---------------------------------------
// 4 waves x 32 rows, TILES tiles/block, barrier-free main loop, rg-split pipeline.
// LDS 50.5 KB -> 3 blocks/CU; live regs ~110 -> fits (256,3) cap without spill.
__global__ __launch_bounds__(256, 3) void k_mlp(
        const float* __restrict__ X,
        const unsigned short* __restrict__ W0Tg,
        const unsigned char* __restrict__ W1f8g,
        const float* __restrict__ b0, const float* __restrict__ b1,
        const float* __restrict__ W2, const float* __restrict__ b2p,
        float* __restrict__ rawOut, unsigned* __restrict__ mcodeOut) {
    __shared__ __align__(16) unsigned short sW0[8192];       // 16 KB W0 frags (swizzled)
    __shared__ __align__(16) unsigned char  sW1f[16384];     // 16 KB W1 fp8 frags (swizzled)
    __shared__ __align__(16) unsigned short sFeat[4][2048];  // 4 KB/wave feats; Hs aliases bytes 0..2047
    __shared__ float sB0[128];
    __shared__ float sB1W2[256];                             // [0..127]=b1, [128..255]=W2
    __shared__ unsigned sMeta[4][2][32];                     // per-wave meta codes, dbuf

    const int t = threadIdx.x, w = t >> 6, l = t & 63;
    const int l15 = l & 15, g = l >> 4;
    const int rx = l15 & 7;

    // stage weights + biases (once per block)
    {
        const uint4* s0 = (const uint4*)W0Tg;  uint4* d0 = (uint4*)sW0;
        const uint4* s1 = (const uint4*)W1f8g; uint4* d1 = (uint4*)sW1f;
#pragma unroll
        for (int i = 0; i < 4; ++i) { d0[i * 256 + t] = s0[i * 256 + t]; d1[i * 256 + t] = s1[i * 256 + t]; }
    }
    if (t < 128) { sB0[t] = b0[t]; sB1W2[t] = b1[t]; sB1W2[128 + t] = W2[t]; }
    const float b2v = b2p[0];
    __syncthreads();   // only barrier

    unsigned short* feat = sFeat[w];
    unsigned char* hsb = (unsigned char*)feat;   // Hs fp8 view: bytes 0..2047 (rows 0..15 region)
    const size_t rowwave0 = (size_t)blockIdx.x * (TILES * TILE_ROWS) + w * 32;
    const int sr = l >> 1, sc = l & 1;           // staging role: row sr, col-half sc

    // ---- prologue: stage tile 0 ----
    float2 pf[16];
    unsigned pmc = 0;
    {
        const float* src = X + (rowwave0 + sr) * LDX + sc * 32;
#pragma unroll
        for (int i = 0; i < 16; ++i) pf[i] = *(const float2*)(src + 2 * i);
        if (sc == 1) {
            float2 mt = *(const float2*)(X + (rowwave0 + sr) * LDX + 64);
            pmc = ((unsigned)((int)mt.x + 1) << 1) | (mt.y > 0.f ? 1u : 0u);
        }
    }
    {
#pragma unroll
        for (int i = 0; i < 4; ++i) {
            uint4 v = make_uint4(pack2(pf[4*i].x, pf[4*i].y),   pack2(pf[4*i+1].x, pf[4*i+1].y),
                                 pack2(pf[4*i+2].x, pf[4*i+2].y), pack2(pf[4*i+3].x, pf[4*i+3].y));
            *(uint4*)(feat + sr * 64 + ((sc * 4 + i) ^ (sr & 7)) * 8) = v;
        }
        if (sc == 1) sMeta[w][0][sr] = pmc;
    }

    for (int tau = 0; tau < TILES; ++tau) {
        const size_t rowb = rowwave0 + (size_t)tau * TILE_ROWS;

        // 0: issue next tile's global loads (in flight across whole iteration)
        if (tau + 1 < TILES) {
            const float* src = X + (rowb + TILE_ROWS + sr) * LDX + sc * 32;
#pragma unroll
            for (int i = 0; i < 16; ++i) pf[i] = *(const float2*)(src + 2 * i);
            if (sc == 1) {
                float2 mt = *(const float2*)(X + (rowb + TILE_ROWS + sr) * LDX + 64);
                pmc = ((unsigned)((int)mt.x + 1) << 1) | (mt.y > 0.f ? 1u : 0u);
            }
        }

        // rg-split pipeline: full chain per 16-row group (acc peak = 32 regs)
#pragma unroll
        for (int rg = 0; rg < 2; ++rg) {
            const int row = rg * 16 + l15;
            // feats fragments (rows rg*16.., units swizzled by row&7 == rx)
            short8 bfr0 = *(const short8*)(feat + row * 64 + ((g)     ^ rx) * 8);
            short8 bfr1 = *(const short8*)(feat + row * 64 + ((4 + g) ^ rx) * 8);

            // GEMM1 (swapped): lane -> h1[row l15][col n*16+g*4+q]
            f32x4 acc[8];
#pragma unroll
            for (int n = 0; n < 8; ++n) acc[n] = (f32x4){0.f, 0.f, 0.f, 0.f};
#pragma unroll
            for (int n = 0; n < 8; ++n) {
                short8 w00 = *(const short8*)(sW0 + (n * 16 + l15) * 64 + ((g)     ^ rx) * 8);
                short8 w01 = *(const short8*)(sW0 + (n * 16 + l15) * 64 + ((4 + g) ^ rx) * 8);
                acc[n] = mfma_bf16(w00, bfr0, acc[n]);
                acc[n] = mfma_bf16(w01, bfr1, acc[n]);
            }

            // bias+relu -> fp8 Hs (2 KB, aliases consumed feats rows 0..15)
#pragma unroll
            for (int n = 0; n < 8; ++n) {
                const int c0 = n * 16 + g * 4;
                float4 bv = *(const float4*)(sB0 + c0);
                unsigned d0 = (unsigned)__builtin_amdgcn_cvt_pk_fp8_f32(
                    fmaxf(acc[n][0] + bv.x, 0.f), fmaxf(acc[n][1] + bv.y, 0.f), 0, false);
                d0 = (unsigned)__builtin_amdgcn_cvt_pk_fp8_f32(
                    fmaxf(acc[n][2] + bv.z, 0.f), fmaxf(acc[n][3] + bv.w, 0.f), (int)d0, true);
                const int u = (2 * n + (g >> 1)) ^ rx;
                *(unsigned*)(hsb + (l15 * 16 + u) * 8 + (g & 1) * 4) = d0;
            }

            // A2 fragments (fp8)
            long a2[4];
#pragma unroll
            for (int kk = 0; kk < 4; ++kk)
                a2[kk] = *(const long*)(hsb + (l15 * 16 + ((kk * 4 + g) ^ rx)) * 8);

            // GEMM2 (fp8) + fused epilogue dot
            float rq[4] = {0.f, 0.f, 0.f, 0.f};
#pragma unroll
            for (int n = 0; n < 8; ++n) {
                f32x4 acc2 = (f32x4){0.f, 0.f, 0.f, 0.f};
                const unsigned char* wrow = sW1f + (n * 16 + l15) * 128;
#pragma unroll
                for (int kk = 0; kk < 4; ++kk) {
                    long bb = *(const long*)(wrow + ((kk * 4 + g) ^ rx) * 8);
                    acc2 = mfma_fp8(a2[kk], bb, acc2);
                }
                float b1v = sB1W2[n * 16 + l15], w2v = sB1W2[128 + n * 16 + l15];
#pragma unroll
                for (int q = 0; q < 4; ++q)
                    rq[q] += fmaxf(acc2[q] + b1v, 0.f) * w2v;
            }

            // reduce over l15, store raw + mcode (NO atomics)
#pragma unroll
            for (int off = 1; off < 16; off <<= 1)
#pragma unroll
                for (int q = 0; q < 4; ++q) rq[q] += __shfl_xor(rq[q], off, 64);
            if (l15 == 0) {
                const size_t m0 = rowb + rg * 16 + g * 4;
                *(float4*)(rawOut + m0) = make_float4(rq[0] + b2v, rq[1] + b2v,
                                                      rq[2] + b2v, rq[3] + b2v);
                unsigned mcs[4];
#pragma unroll
                for (int j = 0; j < 4; ++j) mcs[j] = sMeta[w][tau & 1][rg * 16 + g * 4 + j];
                *(uint4*)(mcodeOut + m0) = make_uint4(mcs[0], mcs[1], mcs[2], mcs[3]);
            }
        }

        // late stage-write: next tile's feats (all feat/Hs reads of this tile done)
        if (tau + 1 < TILES) {
#pragma unroll
            for (int i = 0; i < 4; ++i) {
                uint4 v = make_uint4(pack2(pf[4*i].x, pf[4*i].y),   pack2(pf[4*i+1].x, pf[4*i+1].y),
                                     pack2(pf[4*i+2].x, pf[4*i+2].y), pack2(pf[4*i+3].x, pf[4*i+3].y));
                *(uint4*)(feat + sr * 64 + ((sc * 4 + i) ^ (sr & 7)) * 8) = v;
            }
            if (sc == 1) sMeta[w][(tau + 1) & 1][sr] = pmc;
        }
    }
}

// ---- kernel 2: per-batch-row segment stats via LDS + bias MLP ---------------
// One block per b: reduce 4096 elems over 512 segs in LDS, write segstats.
__global__ __launch_bounds__(256) void k_bstats(
        const float* __restrict__ raw, const unsigned* __restrict__ mcode,
        const float* __restrict__ Wb0, const float* __restrict__ bb0,
        const float* __restrict__ Wb1, const float* __restrict__ bb1,
        float4* __restrict__ segstats) {
    __shared__ unsigned scnt[512];
    __shared__ float    ssum[512];
    __shared__ unsigned smx[512];
    const int b = blockIdx.x, t = threadIdx.x;
    scnt[t] = 0u; ssum[t] = 0.f; smx[t] = 0u;
    scnt[t + 256] = 0u; ssum[t + 256] = 0.f; smx[t + 256] = 0u;
    __syncthreads();
    const int base = b * NC;
#pragma unroll 4
    for (int it = 0; it < 16; ++it) {
        int m = base + it * 256 + t;
        unsigned c = mcode[m];
        if ((c & 1u) && (c >> 1)) {
            int s = (int)(c >> 1) - 1;
            float r = raw[m];
            atomicAdd(&scnt[s], 1u);
            atomicAdd(&ssum[s], r);
            atomicMax(&smx[s], encf(r));
        }
    }
    __syncthreads();
#pragma unroll
    for (int k = 0; k < 2; ++k) {
        int s = t + k * 256;
        unsigned c = scnt[s];
        float smax = (c > 0) ? decf(smx[s]) : 0.f;
        float mean = ssum[s] / fmaxf((float)c, 1.f);
        float multi = (c > 1) ? 1.f : 0.f;
        float bias = 0.f;
        if (c > 1) {
            bias = bb1[0];
#pragma unroll
            for (int j = 0; j < 32; ++j) {
                float h = smax * Wb0[j] + mean * Wb0[32 + j] + (float)c * Wb0[64 + j] + bb0[j];
                bias += fmaxf(h, 0.f) * Wb1[j];
            }
        }
        segstats[b * NG + s] = make_float4(smax, mean, bias, multi);
    }
}

// ---- kernel 3: gather + fair/mask writeout (4 elems/thread) -----------------
__global__ void k_final(const float4* __restrict__ raw4, const uint4* __restrict__ mc4,
                        const float4* __restrict__ segstats, float* __restrict__ out) {
    int i = blockIdx.x * 256 + threadIdx.x;         // group of 4 elems
    float4 rv = raw4[i];
    uint4 mc = mc4[i];
    const float r[4]    = {rv.x, rv.y, rv.z, rv.w};
    const unsigned m[4] = {mc.x, mc.y, mc.z, mc.w};
    const size_t m0 = (size_t)i * 4;
    const int bidx = (int)(m0 >> 12);
    float fair[4], msk[4];
#pragma unroll
    for (int j = 0; j < 4; ++j) {
        msk[j] = (m[j] & 1u) ? 1.0f : 0.0f;
        float f;
        if (m[j] & 1u) {
            f = r[j];
            if (m[j] >> 1) {
                float4 st = segstats[bidx * NG + (int)(m[j] >> 1) - 1];
                if (st.w > 0.5f) f = 1.5f * r[j] - st.y + 0.5f * st.x + st.z;
            }
        } else {
            f = NEGV;
        }
        fair[j] = f;
    }
    *(float4*)(out + m0) = make_float4(fair[0], fair[1], fair[2], fair[3]);
    *(float4*)(out + NELEM + m0) = make_float4(msk[0], msk[1], msk[2], msk[3]);
}

// ---- launch ----------------------------------------------------------------
extern "C" void kernel_launch(void* const* d_in, const int* in_sizes, int n_in,
                              void* d_out, int out_size, void* d_ws, size_t ws_size,
                              hipStream_t stream) {
    const float* X   = (const float*)d_in[0];
    const float* W0  = (const float*)d_in[1];
    const float* b0  = (const float*)d_in[2];
    const float* W1  = (const float*)d_in[3];
    const float* b1  = (const float*)d_in[4];
    const float* W2  = (const float*)d_in[5];
    const float* b2  = (const float*)d_in[6];
    const float* Wb0 = (const float*)d_in[7];
    const float* bb0 = (const float*)d_in[8];
    const float* Wb1 = (const float*)d_in[9];
    const float* bb1 = (const float*)d_in[10];

    char* ws = (char*)d_ws;
    float*          raw      = (float*)(ws + 0);                 // 4 MB
    unsigned*       mcode    = (unsigned*)(ws + 4194304);        // 4 MB
    float4*         segstats = (float4*)(ws + 8388608);          // 2 MB (B*G entries)
    unsigned short* W0T      = (unsigned short*)(ws + 10485760); // 16 KB
    unsigned char*  W1f8s    = (unsigned char*)(ws + 10502144);  // 16 KB

    k_prep<<<96, 256, 0, stream>>>(W0, W1, W0T, W1f8s);
    k_mlp<<<GRID_MLP, 256, 0, stream>>>(X, W0T, W1f8s, b0, b1, W2, b2, raw, mcode);
    k_bstats<<<NB, 256, 0, stream>>>(raw, mcode, Wb0, bb0, Wb1, bb1, segstats);
    k_final<<<NELEM / 1024, 256, 0, stream>>>((const float4*)raw, (const uint4*)mcode,
                                              segstats, (float*)d_out);
}

// Round 9
// 245.007 us; speedup vs baseline: 1.6592x; 1.6592x over previous
//
#include <hip/hip_runtime.h>
#include <hip/hip_bf16.h>

// Problem constants
#define NB   256
#define NC   4096
#define NG   512
#define NH   128
#define NELEM (NB*NC)            // 1048576
#define LDX  66                  // row stride of x_with_meta in floats
#define NEGV (-1000000000.0f)
#define TILES 4                  // 128-row tiles per block
#define TILE_ROWS 128
#define GRID_MLP (NELEM/(TILES*TILE_ROWS))   // 2048

typedef __attribute__((ext_vector_type(8))) short short8;
typedef __attribute__((ext_vector_type(4))) float f32x4;

// truncating f32->bf16 pair pack (threshold makes RNE unnecessary on hot path)
__device__ __forceinline__ unsigned pack2(float x, float y) {
    return (__float_as_uint(y) & 0xFFFF0000u) | (__float_as_uint(x) >> 16);
}
__device__ __forceinline__ unsigned short f2bf(float f) {   // RNE, off hot path
    unsigned u = __float_as_uint(f);
    return (unsigned short)((u + 0x7FFFu + ((u >> 16) & 1u)) >> 16);
}
__device__ __forceinline__ unsigned char f2fp8(float f) {   // e4m3, off hot path
    return (unsigned char)((unsigned)__builtin_amdgcn_cvt_pk_fp8_f32(f, 0.f, 0, false) & 0xFFu);
}
__device__ __forceinline__ unsigned encf(float f) {         // order-preserving f32->u32
    unsigned u = __float_as_uint(f);
    return (u & 0x80000000u) ? ~u : (u | 0x80000000u);
}
__device__ __forceinline__ float decf(unsigned u) {
    unsigned v = (u & 0x80000000u) ? (u ^ 0x80000000u) : ~u;
    return __uint_as_float(v);
}
__device__ __forceinline__ f32x4 mfma_bf16(short8 a, short8 b, f32x4 c) {
    return __builtin_amdgcn_mfma_f32_16x16x32_bf16(a, b, c, 0, 0, 0);
}
__device__ __forceinline__ f32x4 mfma_fp8(long a, long b, f32x4 c) {
    return __builtin_amdgcn_mfma_f32_16x16x32_fp8_fp8(a, b, c, 0, 0, 0);
}

// ---- kernel 0: weight prep --------------------------------------------------
// W0T: [h=128][f=64] bf16 linear (A-frag source for swapped GEMM1)  [r7 layout]
// W1f8s: [j=128][16 units of 8 fp8], unit index XOR-swizzled: u' = u ^ (j&7)
__global__ void k_prep(const float* __restrict__ W0, const float* __restrict__ W1,
                       unsigned short* __restrict__ W0T, unsigned char* __restrict__ W1f8s) {
    int i = blockIdx.x * 256 + threadIdx.x;
    if (i < 8192) {                       // W0T[j][k] = W0[k][j]
        int j = i >> 6, k = i & 63;
        W0T[i] = f2bf(W0[k * NH + j]);
    } else if (i < 24576) {               // W1f8s swizzled: elem (j, c)
        int i2 = i - 8192;
        int j = i2 >> 7, c = i2 & 127;
        W1f8s[(j * 16 + ((c >> 3) ^ (j & 7))) * 8 + (c & 7)] = f2fp8(W1[c * NH + j]);
    }
}

// ---- kernel 1: fused MLP (r7 dataflow, NO atomics, no reg cap) --------------
// 4 waves x 32 rows = 128-row tiles, TILES per block, barrier-free main loop.
// fp8 Hs: 32 rows x 128 B = 4 KB <= 4.5 KB buf. LDS 36.4 KB.
// launch_bounds(256,2): VGPR cap 256 -> allocator lands ~128, zero spill (r3/r6-verified).
__global__ __launch_bounds__(256, 2) void k_mlp(
        const float* __restrict__ X,
        const unsigned short* __restrict__ W0T,
        const unsigned char* __restrict__ W1f8s,
        const float* __restrict__ b0, const float* __restrict__ b1,
        const float* __restrict__ W2, const float* __restrict__ b2p,
        float* __restrict__ rawOut, unsigned* __restrict__ mcodeOut) {
    __shared__ __align__(16) unsigned char sW1f[16384];      // 16 KB W1 fp8 frags (swizzled)
    __shared__ __align__(16) unsigned short sBuf[4][2304];   // 4.5 KB/wave: feats bf16 / Hs fp8 aliased
    __shared__ float sB0[128];
    __shared__ unsigned sMeta[4][2][32];                     // per-wave meta codes, dbuf

    const int t = threadIdx.x, w = t >> 6, l = t & 63;
    const int l15 = l & 15, g = l >> 4;
    const int rx = l15 & 7;

    // stage W1 fp8 (pre-swizzled, linear copy; once per block)
    {
        const uint4* src = (const uint4*)W1f8s;
        uint4* dst = (uint4*)sW1f;
#pragma unroll
        for (int i = 0; i < 4; ++i) dst[i * 256 + t] = src[i * 256 + t];
    }
    if (t < 128) sB0[t] = b0[t];

    // loop-invariant register fragments
    short8 w0f[8][2];
#pragma unroll
    for (int n = 0; n < 8; ++n)
#pragma unroll
        for (int kk = 0; kk < 2; ++kk)
            w0f[n][kk] = *(const short8*)(W0T + (n * 16 + l15) * 64 + kk * 32 + g * 8);
    float b1v[8], w2v[8];
#pragma unroll
    for (int n = 0; n < 8; ++n) { b1v[n] = b1[n * 16 + l15]; w2v[n] = W2[n * 16 + l15]; }
    const float b2v = b2p[0];

    __syncthreads();   // only barrier: sW1f/sB0 ready

    unsigned short* buf = sBuf[w];
    unsigned char* hsb = (unsigned char*)buf;    // Hs fp8 view (4 KB, aliases feats)
    const size_t rowwave0 = (size_t)blockIdx.x * (TILES * TILE_ROWS) + w * 32;
    const int sr = l >> 1, sc = l & 1;   // staging role: row sr, col-half sc

    // ---- prologue: stage tile 0 (coalesced f32 -> bf16 -> own-wave LDS) ----
    float2 pf[16];
    unsigned pmc = 0;
    {
        const float* src = X + (rowwave0 + sr) * LDX + sc * 32;
#pragma unroll
        for (int i = 0; i < 16; ++i) pf[i] = *(const float2*)(src + 2 * i);
        if (sc == 1) {
            float2 mt = *(const float2*)(X + (rowwave0 + sr) * LDX + 64);
            pmc = ((unsigned)((int)mt.x + 1) << 1) | (mt.y > 0.f ? 1u : 0u);
        }
    }
    {
        unsigned pk[16];
#pragma unroll
        for (int i = 0; i < 16; ++i) pk[i] = pack2(pf[i].x, pf[i].y);
        unsigned short* d = buf + sr * 72 + sc * 32;
#pragma unroll
        for (int i = 0; i < 4; ++i)
            ((uint4*)d)[i] = make_uint4(pk[4*i], pk[4*i+1], pk[4*i+2], pk[4*i+3]);
        if (sc == 1) sMeta[w][0][sr] = pmc;
    }

    for (int tau = 0; tau < TILES; ++tau) {
        const size_t rowb = rowwave0 + (size_t)tau * TILE_ROWS;

        // 0: issue next tile's global loads (in flight across whole iteration)
        if (tau + 1 < TILES) {
            const float* src = X + (rowb + TILE_ROWS + sr) * LDX + sc * 32;
#pragma unroll
            for (int i = 0; i < 16; ++i) pf[i] = *(const float2*)(src + 2 * i);
            if (sc == 1) {
                float2 mt = *(const float2*)(X + (rowb + TILE_ROWS + sr) * LDX + 64);
                pmc = ((unsigned)((int)mt.x + 1) << 1) | (mt.y > 0.f ? 1u : 0u);
            }
        }

        // 1: feats fragments (row rg*16+l15, cols kk*32+g*8..+7) -- read BEFORE Hs writes
        short8 bfr[2][2];
#pragma unroll
        for (int rg = 0; rg < 2; ++rg)
#pragma unroll
            for (int kk = 0; kk < 2; ++kk)
                bfr[rg][kk] = *(const short8*)(buf + (rg * 16 + l15) * 72 + kk * 32 + g * 8);

        // 2+3: GEMM1 in two n-halves; acc liveness = 32 regs per half
#pragma unroll
        for (int nh = 0; nh < 2; ++nh) {
            f32x4 acc[4][2];
#pragma unroll
            for (int n4 = 0; n4 < 4; ++n4)
#pragma unroll
                for (int rg = 0; rg < 2; ++rg) acc[n4][rg] = (f32x4){0.f, 0.f, 0.f, 0.f};
#pragma unroll
            for (int n4 = 0; n4 < 4; ++n4) {
                const int n = nh * 4 + n4;
#pragma unroll
                for (int rg = 0; rg < 2; ++rg) {
                    acc[n4][rg] = mfma_bf16(w0f[n][0], bfr[rg][0], acc[n4][rg]);
                    acc[n4][rg] = mfma_bf16(w0f[n][1], bfr[rg][1], acc[n4][rg]);
                }
            }
            // bias+relu -> fp8 quad, write Hs (XOR-swizzled 8B units)
#pragma unroll
            for (int n4 = 0; n4 < 4; ++n4) {
                const int n = nh * 4 + n4;
                const int c0 = n * 16 + g * 4;
                const float bv0 = sB0[c0], bv1 = sB0[c0+1], bv2 = sB0[c0+2], bv3 = sB0[c0+3];
                const int u = (2 * n + (g >> 1)) ^ rx;
#pragma unroll
                for (int rg = 0; rg < 2; ++rg) {
                    unsigned d0 = (unsigned)__builtin_amdgcn_cvt_pk_fp8_f32(
                        fmaxf(acc[n4][rg][0] + bv0, 0.f), fmaxf(acc[n4][rg][1] + bv1, 0.f), 0, false);
                    d0 = (unsigned)__builtin_amdgcn_cvt_pk_fp8_f32(
                        fmaxf(acc[n4][rg][2] + bv2, 0.f), fmaxf(acc[n4][rg][3] + bv3, 0.f), (int)d0, true);
                    *(unsigned*)(hsb + ((rg * 16 + l15) * 16 + u) * 8 + (g & 1) * 4) = d0;
                }
            }
        }

        // 4: A2 fragments (fp8, row rg*16+l15, K elems kk*32+g*8..+7, swizzled)
        long a2[2][4];
#pragma unroll
        for (int rg = 0; rg < 2; ++rg)
#pragma unroll
            for (int kk = 0; kk < 4; ++kk)
                a2[rg][kk] = *(const long*)(hsb + ((rg * 16 + l15) * 16 + ((kk * 4 + g) ^ rx)) * 8);

        // 5: write next tile's feats into buf (all Hs reads issued before; same-wave DS order)
        if (tau + 1 < TILES) {
            unsigned pk[16];
#pragma unroll
            for (int i = 0; i < 16; ++i) pk[i] = pack2(pf[i].x, pf[i].y);
            unsigned short* d = buf + sr * 72 + sc * 32;
#pragma unroll
            for (int i = 0; i < 4; ++i)
                ((uint4*)d)[i] = make_uint4(pk[4*i], pk[4*i+1], pk[4*i+2], pk[4*i+3]);
            if (sc == 1) sMeta[w][(tau + 1) & 1][sr] = pmc;
        }

        // 6: GEMM2 (fp8) + fused epilogue dot (B-frag shared across both rg)
        float rq[2][4] = {{0.f,0.f,0.f,0.f},{0.f,0.f,0.f,0.f}};
#pragma unroll
        for (int n = 0; n < 8; ++n) {
            f32x4 acc2[2] = {(f32x4){0.f,0.f,0.f,0.f}, (f32x4){0.f,0.f,0.f,0.f}};
            const unsigned char* wrow = sW1f + (n * 16 + l15) * 128;
#pragma unroll
            for (int kk = 0; kk < 4; ++kk) {
                long bb = *(const long*)(wrow + ((kk * 4 + g) ^ rx) * 8);
                acc2[0] = mfma_fp8(a2[0][kk], bb, acc2[0]);
                acc2[1] = mfma_fp8(a2[1][kk], bb, acc2[1]);
            }
#pragma unroll
            for (int rg = 0; rg < 2; ++rg)
#pragma unroll
                for (int q = 0; q < 4; ++q)
                    rq[rg][q] += fmaxf(acc2[rg][q] + b1v[n], 0.f) * w2v[n];
        }

        // 7: reduce over l15, store raw + mcode (NO atomics)
#pragma unroll
        for (int off = 1; off < 16; off <<= 1)
#pragma unroll
            for (int rg = 0; rg < 2; ++rg)
#pragma unroll
                for (int q = 0; q < 4; ++q)
                    rq[rg][q] += __shfl_xor(rq[rg][q], off, 64);
        if (l15 == 0) {
#pragma unroll
            for (int rg = 0; rg < 2; ++rg) {
                const size_t m0 = rowb + rg * 16 + g * 4;
                *(float4*)(rawOut + m0) = make_float4(rq[rg][0] + b2v, rq[rg][1] + b2v,
                                                      rq[rg][2] + b2v, rq[rg][3] + b2v);
                unsigned mcs[4];
#pragma unroll
                for (int j = 0; j < 4; ++j) mcs[j] = sMeta[w][tau & 1][rg * 16 + g * 4 + j];
                *(uint4*)(mcodeOut + m0) = make_uint4(mcs[0], mcs[1], mcs[2], mcs[3]);
            }
        }
    }
}

// ---- kernel 2: fused per-batch-row stats + bias MLP + fair writeout ---------
// One block per b: LDS segment reduction over 512 segs, bias MLP, then apply
// fair/mask for the row directly (raw/mcode re-read is L2-resident).
__global__ __launch_bounds__(256) void k_bstats(
        const float* __restrict__ raw, const unsigned* __restrict__ mcode,
        const float* __restrict__ Wb0, const float* __restrict__ bb0,
        const float* __restrict__ Wb1, const float* __restrict__ bb1,
        float* __restrict__ out) {
    __shared__ unsigned scnt[512];
    __shared__ float    ssum[512];
    __shared__ unsigned smx[512];
    __shared__ float4   sstat[512];   // (smax, mean, bias, multi)
    const int b = blockIdx.x, t = threadIdx.x;
    scnt[t] = 0u; ssum[t] = 0.f; smx[t] = 0u;
    scnt[t + 256] = 0u; ssum[t + 256] = 0.f; smx[t + 256] = 0u;
    __syncthreads();
    const int base = b * NC;
#pragma unroll 4
    for (int it = 0; it < 16; ++it) {
        int m = base + it * 256 + t;
        unsigned c = mcode[m];
        if ((c & 1u) && (c >> 1)) {
            int s = (int)(c >> 1) - 1;
            float r = raw[m];
            atomicAdd(&scnt[s], 1u);
            atomicAdd(&ssum[s], r);
            atomicMax(&smx[s], encf(r));
        }
    }
    __syncthreads();
#pragma unroll
    for (int k = 0; k < 2; ++k) {
        int s = t + k * 256;
        unsigned c = scnt[s];
        float smax = (c > 0) ? decf(smx[s]) : 0.f;
        float mean = ssum[s] / fmaxf((float)c, 1.f);
        float multi = (c > 1) ? 1.f : 0.f;
        float bias = 0.f;
        if (c > 1) {
            bias = bb1[0];
#pragma unroll
            for (int j = 0; j < 32; ++j) {
                float h = smax * Wb0[j] + mean * Wb0[32 + j] + (float)c * Wb0[64 + j] + bb0[j];
                bias += fmaxf(h, 0.f) * Wb1[j];
            }
        }
        sstat[s] = make_float4(smax, mean, bias, multi);
    }
    __syncthreads();
    // fair/mask writeout for this row, 4 elems/thread/iter
    const float4* raw4 = (const float4*)raw;
    const uint4*  mc4  = (const uint4*)mcode;
#pragma unroll
    for (int it = 0; it < 4; ++it) {
        int i = b * 1024 + it * 256 + t;       // float4 group index
        float4 rv = raw4[i];
        uint4 mc = mc4[i];
        const float r[4]    = {rv.x, rv.y, rv.z, rv.w};
        const unsigned m[4] = {mc.x, mc.y, mc.z, mc.w};
        float fair[4], msk[4];
#pragma unroll
        for (int j = 0; j < 4; ++j) {
            msk[j] = (m[j] & 1u) ? 1.0f : 0.0f;
            float f;
            if (m[j] & 1u) {
                f = r[j];
                if (m[j] >> 1) {
                    float4 st = sstat[(int)(m[j] >> 1) - 1];
                    if (st.w > 0.5f) f = 1.5f * r[j] - st.y + 0.5f * st.x + st.z;
                }
            } else {
                f = NEGV;
            }
            fair[j] = f;
        }
        const size_t m0 = (size_t)i * 4;
        *(float4*)(out + m0) = make_float4(fair[0], fair[1], fair[2], fair[3]);
        *(float4*)(out + NELEM + m0) = make_float4(msk[0], msk[1], msk[2], msk[3]);
    }
}

// ---- launch ----------------------------------------------------------------
extern "C" void kernel_launch(void* const* d_in, const int* in_sizes, int n_in,
                              void* d_out, int out_size, void* d_ws, size_t ws_size,
                              hipStream_t stream) {
    const float* X   = (const float*)d_in[0];
    const float* W0  = (const float*)d_in[1];
    const float* b0  = (const float*)d_in[2];
    const float* W1  = (const float*)d_in[3];
    const float* b1  = (const float*)d_in[4];
    const float* W2  = (const float*)d_in[5];
    const float* b2  = (const float*)d_in[6];
    const float* Wb0 = (const float*)d_in[7];
    const float* bb0 = (const float*)d_in[8];
    const float* Wb1 = (const float*)d_in[9];
    const float* bb1 = (const float*)d_in[10];

    char* ws = (char*)d_ws;
    float*          raw      = (float*)(ws + 0);                 // 4 MB
    unsigned*       mcode    = (unsigned*)(ws + 4194304);        // 4 MB
    unsigned short* W0T      = (unsigned short*)(ws + 8388608);  // 16 KB
    unsigned char*  W1f8s    = (unsigned char*)(ws + 8404992);   // 16 KB

    k_prep<<<96, 256, 0, stream>>>(W0, W1, W0T, W1f8s);
    k_mlp<<<GRID_MLP, 256, 0, stream>>>(X, W0T, W1f8s, b0, b1, W2, b2, raw, mcode);
    k_bstats<<<NB, 256, 0, stream>>>(raw, mcode, Wb0, bb0, Wb1, bb1, (float*)d_out);
}

// Round 10
// 178.183 us; speedup vs baseline: 2.2815x; 1.3750x over previous
//
#include <hip/hip_runtime.h>
#include <hip/hip_bf16.h>

// Problem constants
#define NB   256
#define NC   4096
#define NG   512
#define NH   128
#define NELEM (NB*NC)            // 1048576
#define LDX  66                  // row stride of x_with_meta in floats
#define NEGV (-1000000000.0f)
#define TILES 8                  // 128-row tiles per block
#define TILE_ROWS 128
#define GRID_MLP (NELEM/(TILES*TILE_ROWS))   // 1024

typedef __attribute__((ext_vector_type(8))) short short8;
typedef __attribute__((ext_vector_type(4))) float f32x4;

// truncating f32->bf16 pair pack
__device__ __forceinline__ unsigned pack2(float x, float y) {
    return (__float_as_uint(y) & 0xFFFF0000u) | (__float_as_uint(x) >> 16);
}
__device__ __forceinline__ unsigned short f2bf(float f) {   // RNE, off hot path
    unsigned u = __float_as_uint(f);
    return (unsigned short)((u + 0x7FFFu + ((u >> 16) & 1u)) >> 16);
}
__device__ __forceinline__ unsigned char f2fp8(float f) {   // e4m3, off hot path
    return (unsigned char)((unsigned)__builtin_amdgcn_cvt_pk_fp8_f32(f, 0.f, 0, false) & 0xFFu);
}
__device__ __forceinline__ unsigned encf(float f) {         // order-preserving f32->u32
    unsigned u = __float_as_uint(f);
    return (u & 0x80000000u) ? ~u : (u | 0x80000000u);
}
__device__ __forceinline__ float decf(unsigned u) {
    unsigned v = (u & 0x80000000u) ? (u ^ 0x80000000u) : ~u;
    return __uint_as_float(v);
}
__device__ __forceinline__ f32x4 mfma_bf16(short8 a, short8 b, f32x4 c) {
    return __builtin_amdgcn_mfma_f32_16x16x32_bf16(a, b, c, 0, 0, 0);
}
__device__ __forceinline__ f32x4 mfma_fp8(long a, long b, f32x4 c) {
    return __builtin_amdgcn_mfma_f32_16x16x32_fp8_fp8(a, b, c, 0, 0, 0);
}

// async global->LDS, 16B per lane, LDS dest = uniform base + lane*16
__device__ __forceinline__ void gload16(const float* g, float* lds) {
    __builtin_amdgcn_global_load_lds(
        (const __attribute__((address_space(1))) void*)g,
        (__attribute__((address_space(3))) void*)lds,
        16, 0, 0);
}

// ---- kernel 0: weight prep (unchanged r9) -----------------------------------
__global__ void k_prep(const float* __restrict__ W0, const float* __restrict__ W1,
                       unsigned short* __restrict__ W0T, unsigned char* __restrict__ W1f8s) {
    int i = blockIdx.x * 256 + threadIdx.x;
    if (i < 8192) {                       // W0T[j][k] = W0[k][j]
        int j = i >> 6, k = i & 63;
        W0T[i] = f2bf(W0[k * NH + j]);
    } else if (i < 24576) {               // W1f8s swizzled: elem (j, c)
        int i2 = i - 8192;
        int j = i2 >> 7, c = i2 & 127;
        W1f8s[(j * 16 + ((c >> 3) ^ (j & 7))) * 8 + (c & 7)] = f2fp8(W1[c * NH + j]);
    }
}

// ---- kernel 1: fused MLP, global_load_lds staging, no prefetch registers ----
// 4 waves x 32 rows, TILES=8, barrier-free loop. Feats f32 in LDS (8KB/wave),
// source-swizzled slots (slot^(row&7)) so reads are conflict-free. fp8 GEMM2.
// LDS 51.2 KB -> 3 blocks/CU; live ~90 arch + ~40 acc -> (256,3) without spill.
__global__ __launch_bounds__(256, 3) void k_mlp(
        const float* __restrict__ X,
        const unsigned short* __restrict__ W0T,
        const unsigned char* __restrict__ W1f8s,
        const float* __restrict__ b0, const float* __restrict__ b1,
        const float* __restrict__ W2, const float* __restrict__ b2p,
        float* __restrict__ rawOut, unsigned* __restrict__ mcodeOut) {
    __shared__ __align__(16) unsigned char sW1f[16384];   // 16 KB W1 fp8 frags (swizzled)
    __shared__ __align__(16) float sFeat[4][2048];        // 8 KB/wave feats f32 (slot-swizzled)
    __shared__ float sB0[128];
    __shared__ float sB1W2[256];                          // [0..127]=b1, [128..255]=W2
    __shared__ __align__(16) unsigned sMeta[4][32];

    const int t = threadIdx.x, w = t >> 6, l = t & 63;
    const int l15 = l & 15, g = l >> 4;
    const int rx = l15 & 7;

    // stage W1 fp8 + biases (once per block)
    {
        const uint4* src = (const uint4*)W1f8s;
        uint4* dst = (uint4*)sW1f;
#pragma unroll
        for (int i = 0; i < 4; ++i) dst[i * 256 + t] = src[i * 256 + t];
    }
    if (t < 128) { sB0[t] = b0[t]; sB1W2[t] = b1[t]; sB1W2[128 + t] = W2[t]; }

    // loop-invariant W0 fragments in registers (32 VGPRs)
    short8 w0f[8][2];
#pragma unroll
    for (int n = 0; n < 8; ++n)
#pragma unroll
        for (int kk = 0; kk < 2; ++kk)
            w0f[n][kk] = *(const short8*)(W0T + (n * 16 + l15) * 64 + kk * 32 + g * 8);
    const float b2v = b2p[0];

    __syncthreads();   // only barrier: sW1f/sB0/sB1W2 ready

    float* fw = sFeat[w];
    unsigned char* hsb = (unsigned char*)fw;     // Hs fp8 view (4 KB, aliases feat rows 0..15)
    const size_t rowwave0 = (size_t)blockIdx.x * (TILES * TILE_ROWS) + w * 32;

    // per-lane gload source offsets (floats): row-in-chunk r4, slot sl, swizzled
    const int r4 = l >> 4, sl = l & 15;
    const int offE = r4 * LDX + ((sl ^ r4) << 2);
    const int offO = r4 * LDX + ((sl ^ (r4 + 4)) << 2);

    // prologue: issue tile-0 staging (8 x 1KB)
    {
        const float* gb = X + rowwave0 * LDX;
#pragma unroll
        for (int k = 0; k < 8; ++k)
            gload16(gb + k * 4 * LDX + ((k & 1) ? offO : offE), fw + k * 256);
    }

    for (int tau = 0; tau < TILES; ++tau) {
        const size_t rowb = rowwave0 + (size_t)tau * TILE_ROWS;

        asm volatile("s_waitcnt vmcnt(0)" ::: "memory");   // tile feats landed
        __builtin_amdgcn_sched_barrier(0);

        // meta for this tile's 32 rows (lines already in L1/L2 from feats gloads)
        if (l < 32) {
            float2 mt = *(const float2*)(X + (rowb + l) * LDX + 64);
            sMeta[w][l] = ((unsigned)((int)mt.x + 1) << 1) | (mt.y > 0.f ? 1u : 0u);
        }

        // feats fragments from f32 LDS (swizzled slots), pack to bf16
        short8 bfr[2][2];
#pragma unroll
        for (int rg = 0; rg < 2; ++rg)
#pragma unroll
            for (int kk = 0; kk < 2; ++kk) {
                const int row = rg * 16 + l15;
                const int u0 = kk * 8 + 2 * g;
                const float* base = fw + row * 64;
                float4 fa = *(const float4*)(base + ((u0 ^ rx) << 2));
                float4 fb = *(const float4*)(base + (((u0 + 1) ^ rx) << 2));
                union { unsigned u[4]; short8 s; } tu;
                tu.u[0] = pack2(fa.x, fa.y); tu.u[1] = pack2(fa.z, fa.w);
                tu.u[2] = pack2(fb.x, fb.y); tu.u[3] = pack2(fb.z, fb.w);
                bfr[rg][kk] = tu.s;
            }

        // GEMM1 in two n-halves (acc liveness 32 regs); bias+relu -> fp8 Hs
#pragma unroll
        for (int nh = 0; nh < 2; ++nh) {
            f32x4 acc[4][2];
#pragma unroll
            for (int n4 = 0; n4 < 4; ++n4)
#pragma unroll
                for (int rg = 0; rg < 2; ++rg) acc[n4][rg] = (f32x4){0.f, 0.f, 0.f, 0.f};
#pragma unroll
            for (int n4 = 0; n4 < 4; ++n4) {
                const int n = nh * 4 + n4;
#pragma unroll
                for (int rg = 0; rg < 2; ++rg) {
                    acc[n4][rg] = mfma_bf16(w0f[n][0], bfr[rg][0], acc[n4][rg]);
                    acc[n4][rg] = mfma_bf16(w0f[n][1], bfr[rg][1], acc[n4][rg]);
                }
            }
#pragma unroll
            for (int n4 = 0; n4 < 4; ++n4) {
                const int n = nh * 4 + n4;
                const int c0 = n * 16 + g * 4;
                const float bv0 = sB0[c0], bv1 = sB0[c0+1], bv2 = sB0[c0+2], bv3 = sB0[c0+3];
                const int u = (2 * n + (g >> 1)) ^ rx;
#pragma unroll
                for (int rg = 0; rg < 2; ++rg) {
                    unsigned d0 = (unsigned)__builtin_amdgcn_cvt_pk_fp8_f32(
                        fmaxf(acc[n4][rg][0] + bv0, 0.f), fmaxf(acc[n4][rg][1] + bv1, 0.f), 0, false);
                    d0 = (unsigned)__builtin_amdgcn_cvt_pk_fp8_f32(
                        fmaxf(acc[n4][rg][2] + bv2, 0.f), fmaxf(acc[n4][rg][3] + bv3, 0.f), (int)d0, true);
                    *(unsigned*)(hsb + ((rg * 16 + l15) * 16 + u) * 8 + (g & 1) * 4) = d0;
                }
            }
        }

        // A2 fragments (fp8, swizzled)
        long a2[2][4];
#pragma unroll
        for (int rg = 0; rg < 2; ++rg)
#pragma unroll
            for (int kk = 0; kk < 4; ++kk)
                a2[rg][kk] = *(const long*)(hsb + ((rg * 16 + l15) * 16 + ((kk * 4 + g) ^ rx)) * 8);

        // all LDS reads of this tile's feat/Hs complete, then issue next staging
        asm volatile("s_waitcnt lgkmcnt(0)" ::: "memory");
        __builtin_amdgcn_sched_barrier(0);
        if (tau + 1 < TILES) {
            const float* gb = X + (rowb + TILE_ROWS) * LDX;
#pragma unroll
            for (int k = 0; k < 8; ++k)
                gload16(gb + k * 4 * LDX + ((k & 1) ? offO : offE), fw + k * 256);
        }
        __builtin_amdgcn_sched_barrier(0);   // keep stores below the gload issues

        // GEMM2 (fp8) + fused epilogue dot (overlaps in-flight staging)
        float rq[2][4] = {{0.f,0.f,0.f,0.f},{0.f,0.f,0.f,0.f}};
#pragma unroll
        for (int n = 0; n < 8; ++n) {
            f32x4 acc2[2] = {(f32x4){0.f,0.f,0.f,0.f}, (f32x4){0.f,0.f,0.f,0.f}};
            const unsigned char* wrow = sW1f + (n * 16 + l15) * 128;
#pragma unroll
            for (int kk = 0; kk < 4; ++kk) {
                long bb = *(const long*)(wrow + ((kk * 4 + g) ^ rx) * 8);
                acc2[0] = mfma_fp8(a2[0][kk], bb, acc2[0]);
                acc2[1] = mfma_fp8(a2[1][kk], bb, acc2[1]);
            }
            const float b1v = sB1W2[n * 16 + l15], w2v = sB1W2[128 + n * 16 + l15];
#pragma unroll
            for (int rg = 0; rg < 2; ++rg)
#pragma unroll
                for (int q = 0; q < 4; ++q)
                    rq[rg][q] += fmaxf(acc2[rg][q] + b1v, 0.f) * w2v;
        }

        // reduce over l15, store raw + mcode (no atomics)
#pragma unroll
        for (int off = 1; off < 16; off <<= 1)
#pragma unroll
            for (int rg = 0; rg < 2; ++rg)
#pragma unroll
                for (int q = 0; q < 4; ++q)
                    rq[rg][q] += __shfl_xor(rq[rg][q], off, 64);
        if (l15 == 0) {
#pragma unroll
            for (int rg = 0; rg < 2; ++rg) {
                const size_t m0 = rowb + rg * 16 + g * 4;
                *(float4*)(rawOut + m0) = make_float4(rq[rg][0] + b2v, rq[rg][1] + b2v,
                                                      rq[rg][2] + b2v, rq[rg][3] + b2v);
                uint4 mcs = *(const uint4*)(&sMeta[w][rg * 16 + g * 4]);
                *(uint4*)(mcodeOut + m0) = mcs;
            }
        }
    }
}

// ---- kernel 2: fused per-batch-row stats + bias MLP + fair writeout ---------
__global__ __launch_bounds__(256) void k_bstats(
        const float* __restrict__ raw, const unsigned* __restrict__ mcode,
        const float* __restrict__ Wb0, const float* __restrict__ bb0,
        const float* __restrict__ Wb1, const float* __restrict__ bb1,
        float* __restrict__ out) {
    __shared__ unsigned scnt[512];
    __shared__ float    ssum[512];
    __shared__ unsigned smx[512];
    __shared__ float4   sstat[512];
    const int b = blockIdx.x, t = threadIdx.x;
    scnt[t] = 0u; ssum[t] = 0.f; smx[t] = 0u;
    scnt[t + 256] = 0u; ssum[t + 256] = 0.f; smx[t + 256] = 0u;
    __syncthreads();
    const int base = b * NC;
#pragma unroll 4
    for (int it = 0; it < 16; ++it) {
        int m = base + it * 256 + t;
        unsigned c = mcode[m];
        if ((c & 1u) && (c >> 1)) {
            int s = (int)(c >> 1) - 1;
            float r = raw[m];
            atomicAdd(&scnt[s], 1u);
            atomicAdd(&ssum[s], r);
            atomicMax(&smx[s], encf(r));
        }
    }
    __syncthreads();
#pragma unroll
    for (int k = 0; k < 2; ++k) {
        int s = t + k * 256;
        unsigned c = scnt[s];
        float smax = (c > 0) ? decf(smx[s]) : 0.f;
        float mean = ssum[s] / fmaxf((float)c, 1.f);
        float multi = (c > 1) ? 1.f : 0.f;
        float bias = 0.f;
        if (c > 1) {
            bias = bb1[0];
#pragma unroll
            for (int j = 0; j < 32; ++j) {
                float h = smax * Wb0[j] + mean * Wb0[32 + j] + (float)c * Wb0[64 + j] + bb0[j];
                bias += fmaxf(h, 0.f) * Wb1[j];
            }
        }
        sstat[s] = make_float4(smax, mean, bias, multi);
    }
    __syncthreads();
    const float4* raw4 = (const float4*)raw;
    const uint4*  mc4  = (const uint4*)mcode;
#pragma unroll
    for (int it = 0; it < 4; ++it) {
        int i = b * 1024 + it * 256 + t;
        float4 rv = raw4[i];
        uint4 mc = mc4[i];
        const float r[4]    = {rv.x, rv.y, rv.z, rv.w};
        const unsigned m[4] = {mc.x, mc.y, mc.z, mc.w};
        float fair[4], msk[4];
#pragma unroll
        for (int j = 0; j < 4; ++j) {
            msk[j] = (m[j] & 1u) ? 1.0f : 0.0f;
            float f;
            if (m[j] & 1u) {
                f = r[j];
                if (m[j] >> 1) {
                    float4 st = sstat[(int)(m[j] >> 1) - 1];
                    if (st.w > 0.5f) f = 1.5f * r[j] - st.y + 0.5f * st.x + st.z;
                }
            } else {
                f = NEGV;
            }
            fair[j] = f;
        }
        const size_t m0 = (size_t)i * 4;
        *(float4*)(out + m0) = make_float4(fair[0], fair[1], fair[2], fair[3]);
        *(float4*)(out + NELEM + m0) = make_float4(msk[0], msk[1], msk[2], msk[3]);
    }
}

// ---- launch ----------------------------------------------------------------
extern "C" void kernel_launch(void* const* d_in, const int* in_sizes, int n_in,
                              void* d_out, int out_size, void* d_ws, size_t ws_size,
                              hipStream_t stream) {
    const float* X   = (const float*)d_in[0];
    const float* W0  = (const float*)d_in[1];
    const float* b0  = (const float*)d_in[2];
    const float* W1  = (const float*)d_in[3];
    const float* b1  = (const float*)d_in[4];
    const float* W2  = (const float*)d_in[5];
    const float* b2  = (const float*)d_in[6];
    const float* Wb0 = (const float*)d_in[7];
    const float* bb0 = (const float*)d_in[8];
    const float* Wb1 = (const float*)d_in[9];
    const float* bb1 = (const float*)d_in[10];

    char* ws = (char*)d_ws;
    float*          raw      = (float*)(ws + 0);                 // 4 MB
    unsigned*       mcode    = (unsigned*)(ws + 4194304);        // 4 MB
    unsigned short* W0T      = (unsigned short*)(ws + 8388608);  // 16 KB
    unsigned char*  W1f8s    = (unsigned char*)(ws + 8404992);   // 16 KB

    k_prep<<<96, 256, 0, stream>>>(W0, W1, W0T, W1f8s);
    k_mlp<<<GRID_MLP, 256, 0, stream>>>(X, W0T, W1f8s, b0, b1, W2, b2, raw, mcode);
    k_bstats<<<NB, 256, 0, stream>>>(raw, mcode, Wb0, bb0, Wb1, bb1, (float*)d_out);
}

// Round 11
// 123.862 us; speedup vs baseline: 3.2820x; 1.4386x over previous
//
#include <hip/hip_runtime.h>
#include <hip/hip_bf16.h>

// Problem constants
#define NB   256
#define NC   4096
#define NG   512
#define NH   128
#define NELEM (NB*NC)            // 1048576
#define LDX  66                  // row stride of x_with_meta in floats
#define NEGV (-1000000000.0f)
#define TILES 16                 // 128-row tiles per block
#define TILE_ROWS 128
#define GRID_MLP (NELEM/(TILES*TILE_ROWS))   // 512 = 2 blocks/CU exactly, 1 round

typedef __attribute__((ext_vector_type(8))) short short8;
typedef __attribute__((ext_vector_type(4))) float f32x4;

// truncating f32->bf16 pair pack
__device__ __forceinline__ unsigned pack2(float x, float y) {
    return (__float_as_uint(y) & 0xFFFF0000u) | (__float_as_uint(x) >> 16);
}
__device__ __forceinline__ unsigned short f2bf(float f) {   // RNE, off hot path
    unsigned u = __float_as_uint(f);
    return (unsigned short)((u + 0x7FFFu + ((u >> 16) & 1u)) >> 16);
}
__device__ __forceinline__ unsigned char f2fp8(float f) {   // e4m3, off hot path
    return (unsigned char)((unsigned)__builtin_amdgcn_cvt_pk_fp8_f32(f, 0.f, 0, false) & 0xFFu);
}
__device__ __forceinline__ unsigned encf(float f) {         // order-preserving f32->u32
    unsigned u = __float_as_uint(f);
    return (u & 0x80000000u) ? ~u : (u | 0x80000000u);
}
__device__ __forceinline__ float decf(unsigned u) {
    unsigned v = (u & 0x80000000u) ? (u ^ 0x80000000u) : ~u;
    return __uint_as_float(v);
}
__device__ __forceinline__ f32x4 mfma_bf16(short8 a, short8 b, f32x4 c) {
    return __builtin_amdgcn_mfma_f32_16x16x32_bf16(a, b, c, 0, 0, 0);
}
__device__ __forceinline__ f32x4 mfma_fp8(long a, long b, f32x4 c) {
    return __builtin_amdgcn_mfma_f32_16x16x32_fp8_fp8(a, b, c, 0, 0, 0);
}

// async global->LDS, 16B per lane, LDS dest = uniform base + lane*16
__device__ __forceinline__ void gload16(const float* g, float* lds) {
    __builtin_amdgcn_global_load_lds(
        (const __attribute__((address_space(1))) void*)g,
        (__attribute__((address_space(3))) void*)lds,
        16, 0, 0);
}

// ---- kernel 0: weight prep (unchanged) --------------------------------------
__global__ void k_prep(const float* __restrict__ W0, const float* __restrict__ W1,
                       unsigned short* __restrict__ W0T, unsigned char* __restrict__ W1f8s) {
    int i = blockIdx.x * 256 + threadIdx.x;
    if (i < 8192) {                       // W0T[j][k] = W0[k][j]
        int j = i >> 6, k = i & 63;
        W0T[i] = f2bf(W0[k * NH + j]);
    } else if (i < 24576) {               // W1f8s swizzled: elem (j, c)
        int i2 = i - 8192;
        int j = i2 >> 7, c = i2 & 127;
        W1f8s[(j * 16 + ((c >> 3) ^ (j & 7))) * 8 + (c & 7)] = f2fp8(W1[c * NH + j]);
    }
}

// ---- kernel 1: fused MLP, full-tile prefetch window --------------------------
// 4 waves x 32 rows, TILES=16, barrier-free. Dedicated Hs buffer (no fw alias)
// -> next-tile gloads issue at TILE TOP; meta via register+shfl (no LDS stall).
// LDS 65.5 KB -> 2 blocks/CU.
__global__ __launch_bounds__(256, 3) void k_mlp(
        const float* __restrict__ X,
        const unsigned short* __restrict__ W0T,
        const unsigned char* __restrict__ W1f8s,
        const float* __restrict__ b0, const float* __restrict__ b1,
        const float* __restrict__ W2, const float* __restrict__ b2p,
        float* __restrict__ rawOut, unsigned* __restrict__ mcodeOut) {
    __shared__ __align__(16) unsigned char sW1f[16384];    // 16 KB W1 fp8 frags (swizzled)
    __shared__ __align__(16) float sFeat[4][2048];         // 8 KB/wave feats f32 (src-swizzled)
    __shared__ __align__(16) unsigned char sHs[4][4096];   // 4 KB/wave fp8 Hs (dedicated!)
    __shared__ float sB0[128];
    __shared__ float sB1W2[256];                           // [0..127]=b1, [128..255]=W2

    const int t = threadIdx.x, w = t >> 6, l = t & 63;
    const int l15 = l & 15, g = l >> 4;
    const int rx = l15 & 7;

    // stage W1 fp8 + biases (once per block)
    {
        const uint4* src = (const uint4*)W1f8s;
        uint4* dst = (uint4*)sW1f;
#pragma unroll
        for (int i = 0; i < 4; ++i) dst[i * 256 + t] = src[i * 256 + t];
    }
    if (t < 128) { sB0[t] = b0[t]; sB1W2[t] = b1[t]; sB1W2[128 + t] = W2[t]; }

    // loop-invariant W0 fragments in registers (32 VGPRs)
    short8 w0f[8][2];
#pragma unroll
    for (int n = 0; n < 8; ++n)
#pragma unroll
        for (int kk = 0; kk < 2; ++kk)
            w0f[n][kk] = *(const short8*)(W0T + (n * 16 + l15) * 64 + kk * 32 + g * 8);
    const float b2v = b2p[0];

    __syncthreads();   // only barrier: sW1f/sB0/sB1W2 ready

    float* fw = sFeat[w];
    unsigned char* hs = sHs[w];
    const size_t rowwave0 = (size_t)blockIdx.x * (TILES * TILE_ROWS) + w * 32;

    // per-lane gload source offsets (floats): row-in-chunk r4, slot sl, swizzled
    const int r4 = l >> 4, sl = l & 15;
    const int offE = r4 * LDX + ((sl ^ r4) << 2);
    const int offO = r4 * LDX + ((sl ^ (r4 + 4)) << 2);

    // prologue: issue tile-0 staging (8 x 1KB) + tile-0 meta
    {
        const float* gb = X + rowwave0 * LDX;
#pragma unroll
        for (int k = 0; k < 8; ++k)
            gload16(gb + k * 4 * LDX + ((k & 1) ? offO : offE), fw + k * 256);
    }
    float2 mt = make_float2(0.f, 0.f), mtN = make_float2(0.f, 0.f);
    if (l < 32) mt = *(const float2*)(X + (rowwave0 + l) * LDX + 64);

    for (int tau = 0; tau < TILES; ++tau) {
        const size_t rowb = rowwave0 + (size_t)tau * TILE_ROWS;

        asm volatile("s_waitcnt vmcnt(0)" ::: "memory");   // this tile's feats landed
        __builtin_amdgcn_sched_barrier(0);

        // feats fragments from f32 LDS (swizzled slots), pack to bf16
        short8 bfr[2][2];
#pragma unroll
        for (int rg = 0; rg < 2; ++rg)
#pragma unroll
            for (int kk = 0; kk < 2; ++kk) {
                const int row = rg * 16 + l15;
                const int u0 = kk * 8 + 2 * g;
                const float* base = fw + row * 64;
                float4 fa = *(const float4*)(base + ((u0 ^ rx) << 2));
                float4 fb = *(const float4*)(base + (((u0 + 1) ^ rx) << 2));
                union { unsigned u[4]; short8 s; } tu;
                tu.u[0] = pack2(fa.x, fa.y); tu.u[1] = pack2(fa.z, fa.w);
                tu.u[2] = pack2(fb.x, fb.y); tu.u[3] = pack2(fb.z, fb.w);
                bfr[rg][kk] = tu.s;
            }

        // fw fully consumed -> issue next tile's staging NOW (full-tile overlap)
        asm volatile("s_waitcnt lgkmcnt(0)" ::: "memory");
        __builtin_amdgcn_sched_barrier(0);
        if (tau + 1 < TILES) {
            const float* gb = X + (rowb + TILE_ROWS) * LDX;
#pragma unroll
            for (int k = 0; k < 8; ++k)
                gload16(gb + k * 4 * LDX + ((k & 1) ? offO : offE), fw + k * 256);
            if (l < 32) mtN = *(const float2*)(X + (rowb + TILE_ROWS + l) * LDX + 64);
        }
        __builtin_amdgcn_sched_barrier(0);   // pin gload issues before compute

        // GEMM1 in two n-halves (acc liveness 32 regs); bias+relu -> fp8 Hs
#pragma unroll
        for (int nh = 0; nh < 2; ++nh) {
            f32x4 acc[4][2];
#pragma unroll
            for (int n4 = 0; n4 < 4; ++n4)
#pragma unroll
                for (int rg = 0; rg < 2; ++rg) acc[n4][rg] = (f32x4){0.f, 0.f, 0.f, 0.f};
#pragma unroll
            for (int n4 = 0; n4 < 4; ++n4) {
                const int n = nh * 4 + n4;
#pragma unroll
                for (int rg = 0; rg < 2; ++rg) {
                    acc[n4][rg] = mfma_bf16(w0f[n][0], bfr[rg][0], acc[n4][rg]);
                    acc[n4][rg] = mfma_bf16(w0f[n][1], bfr[rg][1], acc[n4][rg]);
                }
            }
#pragma unroll
            for (int n4 = 0; n4 < 4; ++n4) {
                const int n = nh * 4 + n4;
                const int c0 = n * 16 + g * 4;
                const float bv0 = sB0[c0], bv1 = sB0[c0+1], bv2 = sB0[c0+2], bv3 = sB0[c0+3];
                const int u = (2 * n + (g >> 1)) ^ rx;
#pragma unroll
                for (int rg = 0; rg < 2; ++rg) {
                    unsigned d0 = (unsigned)__builtin_amdgcn_cvt_pk_fp8_f32(
                        fmaxf(acc[n4][rg][0] + bv0, 0.f), fmaxf(acc[n4][rg][1] + bv1, 0.f), 0, false);
                    d0 = (unsigned)__builtin_amdgcn_cvt_pk_fp8_f32(
                        fmaxf(acc[n4][rg][2] + bv2, 0.f), fmaxf(acc[n4][rg][3] + bv3, 0.f), (int)d0, true);
                    *(unsigned*)(hs + ((rg * 16 + l15) * 16 + u) * 8 + (g & 1) * 4) = d0;
                }
            }
        }

        // A2 fragments (fp8, swizzled) from dedicated Hs
        long a2[2][4];
#pragma unroll
        for (int rg = 0; rg < 2; ++rg)
#pragma unroll
            for (int kk = 0; kk < 4; ++kk)
                a2[rg][kk] = *(const long*)(hs + ((rg * 16 + l15) * 16 + ((kk * 4 + g) ^ rx)) * 8);

        // GEMM2 (fp8) + fused epilogue dot (overlaps in-flight staging)
        float rq[2][4] = {{0.f,0.f,0.f,0.f},{0.f,0.f,0.f,0.f}};
#pragma unroll
        for (int n = 0; n < 8; ++n) {
            f32x4 acc2[2] = {(f32x4){0.f,0.f,0.f,0.f}, (f32x4){0.f,0.f,0.f,0.f}};
            const unsigned char* wrow = sW1f + (n * 16 + l15) * 128;
#pragma unroll
            for (int kk = 0; kk < 4; ++kk) {
                long bb = *(const long*)(wrow + ((kk * 4 + g) ^ rx) * 8);
                acc2[0] = mfma_fp8(a2[0][kk], bb, acc2[0]);
                acc2[1] = mfma_fp8(a2[1][kk], bb, acc2[1]);
            }
            const float b1v = sB1W2[n * 16 + l15], w2v = sB1W2[128 + n * 16 + l15];
#pragma unroll
            for (int rg = 0; rg < 2; ++rg)
#pragma unroll
                for (int q = 0; q < 4; ++q)
                    rq[rg][q] += fmaxf(acc2[rg][q] + b1v, 0.f) * w2v;
        }

        // reduce over l15, meta via shuffle (no LDS), store raw + mcode
#pragma unroll
        for (int off = 1; off < 16; off <<= 1)
#pragma unroll
            for (int rg = 0; rg < 2; ++rg)
#pragma unroll
                for (int q = 0; q < 4; ++q)
                    rq[rg][q] += __shfl_xor(rq[rg][q], off, 64);
        const unsigned pmcu = ((unsigned)((int)mt.x + 1) << 1) | (mt.y > 0.f ? 1u : 0u);
        if (l15 == 0) {
#pragma unroll
            for (int rg = 0; rg < 2; ++rg) {
                const size_t m0 = rowb + rg * 16 + g * 4;
                *(float4*)(rawOut + m0) = make_float4(rq[rg][0] + b2v, rq[rg][1] + b2v,
                                                      rq[rg][2] + b2v, rq[rg][3] + b2v);
            }
        }
        uint4 mcs;
#pragma unroll
        for (int rg = 0; rg < 2; ++rg) {
            const int srow = rg * 16 + g * 4;
            mcs.x = __shfl(pmcu, srow + 0, 64);
            mcs.y = __shfl(pmcu, srow + 1, 64);
            mcs.z = __shfl(pmcu, srow + 2, 64);
            mcs.w = __shfl(pmcu, srow + 3, 64);
            if (l15 == 0) *(uint4*)(mcodeOut + rowb + srow) = mcs;
        }
        mt = mtN;
    }
}

// ---- kernel 2: fused per-batch-row stats + bias MLP + fair writeout ---------
__global__ __launch_bounds__(256) void k_bstats(
        const float* __restrict__ raw, const unsigned* __restrict__ mcode,
        const float* __restrict__ Wb0, const float* __restrict__ bb0,
        const float* __restrict__ Wb1, const float* __restrict__ bb1,
        float* __restrict__ out) {
    __shared__ unsigned scnt[512];
    __shared__ float    ssum[512];
    __shared__ unsigned smx[512];
    __shared__ float4   sstat[512];
    const int b = blockIdx.x, t = threadIdx.x;
    scnt[t] = 0u; ssum[t] = 0.f; smx[t] = 0u;
    scnt[t + 256] = 0u; ssum[t + 256] = 0.f; smx[t + 256] = 0u;
    __syncthreads();
    const int base = b * NC;
#pragma unroll 4
    for (int it = 0; it < 16; ++it) {
        int m = base + it * 256 + t;
        unsigned c = mcode[m];
        if ((c & 1u) && (c >> 1)) {
            int s = (int)(c >> 1) - 1;
            float r = raw[m];
            atomicAdd(&scnt[s], 1u);
            atomicAdd(&ssum[s], r);
            atomicMax(&smx[s], encf(r));
        }
    }
    __syncthreads();
#pragma unroll
    for (int k = 0; k < 2; ++k) {
        int s = t + k * 256;
        unsigned c = scnt[s];
        float smax = (c > 0) ? decf(smx[s]) : 0.f;
        float mean = ssum[s] / fmaxf((float)c, 1.f);
        float multi = (c > 1) ? 1.f : 0.f;
        float bias = 0.f;
        if (c > 1) {
            bias = bb1[0];
#pragma unroll
            for (int j = 0; j < 32; ++j) {
                float h = smax * Wb0[j] + mean * Wb0[32 + j] + (float)c * Wb0[64 + j] + bb0[j];
                bias += fmaxf(h, 0.f) * Wb1[j];
            }
        }
        sstat[s] = make_float4(smax, mean, bias, multi);
    }
    __syncthreads();
    const float4* raw4 = (const float4*)raw;
    const uint4*  mc4  = (const uint4*)mcode;
#pragma unroll
    for (int it = 0; it < 4; ++it) {
        int i = b * 1024 + it * 256 + t;
        float4 rv = raw4[i];
        uint4 mc = mc4[i];
        const float r[4]    = {rv.x, rv.y, rv.z, rv.w};
        const unsigned m[4] = {mc.x, mc.y, mc.z, mc.w};
        float fair[4], msk[4];
#pragma unroll
        for (int j = 0; j < 4; ++j) {
            msk[j] = (m[j] & 1u) ? 1.0f : 0.0f;
            float f;
            if (m[j] & 1u) {
                f = r[j];
                if (m[j] >> 1) {
                    float4 st = sstat[(int)(m[j] >> 1) - 1];
                    if (st.w > 0.5f) f = 1.5f * r[j] - st.y + 0.5f * st.x + st.z;
                }
            } else {
                f = NEGV;
            }
            fair[j] = f;
        }
        const size_t m0 = (size_t)i * 4;
        *(float4*)(out + m0) = make_float4(fair[0], fair[1], fair[2], fair[3]);
        *(float4*)(out + NELEM + m0) = make_float4(msk[0], msk[1], msk[2], msk[3]);
    }
}

// ---- launch ----------------------------------------------------------------
extern "C" void kernel_launch(void* const* d_in, const int* in_sizes, int n_in,
                              void* d_out, int out_size, void* d_ws, size_t ws_size,
                              hipStream_t stream) {
    const float* X   = (const float*)d_in[0];
    const float* W0  = (const float*)d_in[1];
    const float* b0  = (const float*)d_in[2];
    const float* W1  = (const float*)d_in[3];
    const float* b1  = (const float*)d_in[4];
    const float* W2  = (const float*)d_in[5];
    const float* b2  = (const float*)d_in[6];
    const float* Wb0 = (const float*)d_in[7];
    const float* bb0 = (const float*)d_in[8];
    const float* Wb1 = (const float*)d_in[9];
    const float* bb1 = (const float*)d_in[10];

    char* ws = (char*)d_ws;
    float*          raw      = (float*)(ws + 0);                 // 4 MB
    unsigned*       mcode    = (unsigned*)(ws + 4194304);        // 4 MB
    unsigned short* W0T      = (unsigned short*)(ws + 8388608);  // 16 KB
    unsigned char*  W1f8s    = (unsigned char*)(ws + 8404992);   // 16 KB

    k_prep<<<96, 256, 0, stream>>>(W0, W1, W0T, W1f8s);
    k_mlp<<<GRID_MLP, 256, 0, stream>>>(X, W0T, W1f8s, b0, b1, W2, b2, raw, mcode);
    k_bstats<<<NB, 256, 0, stream>>>(raw, mcode, Wb0, bb0, Wb1, bb1, (float*)d_out);
}

// Round 12
// 89.929 us; speedup vs baseline: 4.5204x; 1.3773x over previous
//
#include <hip/hip_runtime.h>
#include <hip/hip_bf16.h>

// Problem constants
#define NB   256
#define NC   4096
#define NG   512
#define NH   128
#define NELEM (NB*NC)            // 1048576
#define LDX  66                  // row stride of x_with_meta in floats
#define NEGV (-1000000000.0f)
#define TILES 16                 // 128-row tiles per block
#define TILE_ROWS 128
#define GRID_MLP (NELEM/(TILES*TILE_ROWS))   // 512 = 2 blocks/CU exactly, 1 round

typedef __attribute__((ext_vector_type(8))) short short8;
typedef __attribute__((ext_vector_type(4))) float f32x4;

// truncating f32->bf16 pair pack
__device__ __forceinline__ unsigned pack2(float x, float y) {
    return (__float_as_uint(y) & 0xFFFF0000u) | (__float_as_uint(x) >> 16);
}
__device__ __forceinline__ unsigned short f2bf(float f) {   // RNE, off hot path
    unsigned u = __float_as_uint(f);
    return (unsigned short)((u + 0x7FFFu + ((u >> 16) & 1u)) >> 16);
}
__device__ __forceinline__ unsigned char f2fp8(float f) {   // e4m3, off hot path
    return (unsigned char)((unsigned)__builtin_amdgcn_cvt_pk_fp8_f32(f, 0.f, 0, false) & 0xFFu);
}
__device__ __forceinline__ unsigned encf(float f) {         // order-preserving f32->u32
    unsigned u = __float_as_uint(f);
    return (u & 0x80000000u) ? ~u : (u | 0x80000000u);
}
__device__ __forceinline__ float decf(unsigned u) {
    unsigned v = (u & 0x80000000u) ? (u ^ 0x80000000u) : ~u;
    return __uint_as_float(v);
}
__device__ __forceinline__ f32x4 mfma_bf16(short8 a, short8 b, f32x4 c) {
    return __builtin_amdgcn_mfma_f32_16x16x32_bf16(a, b, c, 0, 0, 0);
}
__device__ __forceinline__ f32x4 mfma_fp8(long a, long b, f32x4 c) {
    return __builtin_amdgcn_mfma_f32_16x16x32_fp8_fp8(a, b, c, 0, 0, 0);
}

// async global->LDS, 16B per lane, LDS dest = uniform base + lane*16
__device__ __forceinline__ void gload16(const float* g, float* lds) {
    __builtin_amdgcn_global_load_lds(
        (const __attribute__((address_space(1))) void*)g,
        (__attribute__((address_space(3))) void*)lds,
        16, 0, 0);
}

// ---- kernel 0: weight prep (unchanged) --------------------------------------
__global__ void k_prep(const float* __restrict__ W0, const float* __restrict__ W1,
                       unsigned short* __restrict__ W0T, unsigned char* __restrict__ W1f8s) {
    int i = blockIdx.x * 256 + threadIdx.x;
    if (i < 8192) {                       // W0T[j][k] = W0[k][j]
        int j = i >> 6, k = i & 63;
        W0T[i] = f2bf(W0[k * NH + j]);
    } else if (i < 24576) {               // W1f8s swizzled: elem (j, c)
        int i2 = i - 8192;
        int j = i2 >> 7, c = i2 & 127;
        W1f8s[(j * 16 + ((c >> 3) ^ (j & 7))) * 8 + (c & 7)] = f2fp8(W1[c * NH + j]);
    }
}

// ---- kernel 1: fused MLP, counted-vmcnt pipeline ------------------------------
// 4 waves x 32 rows, TILES=16, barrier-free. Per-iter VMEM order (pinned by
// sched_barriers): [8 gloads t+1][mtN load][compute][3 stores t]. Tile-top wait
// is vmcnt(3): gloads+meta landed, stores float across the boundary.
// Meta: lane l<32 owns row rowb+l, stores its own mcode dword (no shfl).
__global__ __launch_bounds__(256, 2) void k_mlp(
        const float* __restrict__ X,
        const unsigned short* __restrict__ W0T,
        const unsigned char* __restrict__ W1f8s,
        const float* __restrict__ b0, const float* __restrict__ b1,
        const float* __restrict__ W2, const float* __restrict__ b2p,
        float* __restrict__ rawOut, unsigned* __restrict__ mcodeOut) {
    __shared__ __align__(16) unsigned char sW1f[16384];    // 16 KB W1 fp8 frags (swizzled)
    __shared__ __align__(16) float sFeat[4][2048];         // 8 KB/wave feats f32 (src-swizzled)
    __shared__ __align__(16) unsigned char sHs[4][4096];   // 4 KB/wave fp8 Hs (dedicated)
    __shared__ float sB0[128];
    __shared__ float sB1W2[256];                           // [0..127]=b1, [128..255]=W2

    const int t = threadIdx.x, w = t >> 6, l = t & 63;
    const int l15 = l & 15, g = l >> 4;
    const int rx = l15 & 7;

    // stage W1 fp8 + biases (once per block)
    {
        const uint4* src = (const uint4*)W1f8s;
        uint4* dst = (uint4*)sW1f;
#pragma unroll
        for (int i = 0; i < 4; ++i) dst[i * 256 + t] = src[i * 256 + t];
    }
    if (t < 128) { sB0[t] = b0[t]; sB1W2[t] = b1[t]; sB1W2[128 + t] = W2[t]; }

    // loop-invariant W0 fragments in registers (32 VGPRs)
    short8 w0f[8][2];
#pragma unroll
    for (int n = 0; n < 8; ++n)
#pragma unroll
        for (int kk = 0; kk < 2; ++kk)
            w0f[n][kk] = *(const short8*)(W0T + (n * 16 + l15) * 64 + kk * 32 + g * 8);
    const float b2v = b2p[0];

    __syncthreads();   // only barrier: sW1f/sB0/sB1W2 ready

    float* fw = sFeat[w];
    unsigned char* hs = sHs[w];
    const size_t rowwave0 = (size_t)blockIdx.x * (TILES * TILE_ROWS) + w * 32;

    // per-lane gload source offsets (floats): row-in-chunk r4, slot sl, swizzled
    const int r4 = l >> 4, sl = l & 15;
    const int offE = r4 * LDX + ((sl ^ r4) << 2);
    const int offO = r4 * LDX + ((sl ^ (r4 + 4)) << 2);

    // prologue: issue tile-0 staging (8 x 1KB) + tile-0 meta
    {
        const float* gb = X + rowwave0 * LDX;
#pragma unroll
        for (int k = 0; k < 8; ++k)
            gload16(gb + k * 4 * LDX + ((k & 1) ? offO : offE), fw + k * 256);
    }
    float2 mt = make_float2(0.f, 0.f), mtN = make_float2(0.f, 0.f);
    if (l < 32) mt = *(const float2*)(X + (rowwave0 + l) * LDX + 64);

    for (int tau = 0; tau < TILES; ++tau) {
        const size_t rowb = rowwave0 + (size_t)tau * TILE_ROWS;

        // counted wait: feats+meta landed; previous tile's 3 stores may float
        if (tau == 0) asm volatile("s_waitcnt vmcnt(0)" ::: "memory");
        else         asm volatile("s_waitcnt vmcnt(3)" ::: "memory");
        __builtin_amdgcn_sched_barrier(0);

        // feats fragments from f32 LDS (swizzled slots), pack to bf16
        short8 bfr[2][2];
#pragma unroll
        for (int rg = 0; rg < 2; ++rg)
#pragma unroll
            for (int kk = 0; kk < 2; ++kk) {
                const int row = rg * 16 + l15;
                const int u0 = kk * 8 + 2 * g;
                const float* base = fw + row * 64;
                float4 fa = *(const float4*)(base + ((u0 ^ rx) << 2));
                float4 fb = *(const float4*)(base + (((u0 + 1) ^ rx) << 2));
                union { unsigned u[4]; short8 s; } tu;
                tu.u[0] = pack2(fa.x, fa.y); tu.u[1] = pack2(fa.z, fa.w);
                tu.u[2] = pack2(fb.x, fb.y); tu.u[3] = pack2(fb.z, fb.w);
                bfr[rg][kk] = tu.s;
            }

        // fw fully consumed -> issue next tile's staging NOW (full-tile overlap)
        asm volatile("s_waitcnt lgkmcnt(0)" ::: "memory");
        __builtin_amdgcn_sched_barrier(0);
        if (tau + 1 < TILES) {
            const float* gb = X + (rowb + TILE_ROWS) * LDX;
#pragma unroll
            for (int k = 0; k < 8; ++k)
                gload16(gb + k * 4 * LDX + ((k & 1) ? offO : offE), fw + k * 256);
            if (l < 32) mtN = *(const float2*)(X + (rowb + TILE_ROWS + l) * LDX + 64);
        }
        __builtin_amdgcn_sched_barrier(0);   // pin gload issues before compute

        // GEMM1 in two n-halves (acc liveness 32 regs); bias+relu -> fp8 Hs
#pragma unroll
        for (int nh = 0; nh < 2; ++nh) {
            f32x4 acc[4][2];
#pragma unroll
            for (int n4 = 0; n4 < 4; ++n4)
#pragma unroll
                for (int rg = 0; rg < 2; ++rg) acc[n4][rg] = (f32x4){0.f, 0.f, 0.f, 0.f};
#pragma unroll
            for (int n4 = 0; n4 < 4; ++n4) {
                const int n = nh * 4 + n4;
#pragma unroll
                for (int rg = 0; rg < 2; ++rg) {
                    acc[n4][rg] = mfma_bf16(w0f[n][0], bfr[rg][0], acc[n4][rg]);
                    acc[n4][rg] = mfma_bf16(w0f[n][1], bfr[rg][1], acc[n4][rg]);
                }
            }
#pragma unroll
            for (int n4 = 0; n4 < 4; ++n4) {
                const int n = nh * 4 + n4;
                const int c0 = n * 16 + g * 4;
                const float bv0 = sB0[c0], bv1 = sB0[c0+1], bv2 = sB0[c0+2], bv3 = sB0[c0+3];
                const int u = (2 * n + (g >> 1)) ^ rx;
#pragma unroll
                for (int rg = 0; rg < 2; ++rg) {
                    unsigned d0 = (unsigned)__builtin_amdgcn_cvt_pk_fp8_f32(
                        fmaxf(acc[n4][rg][0] + bv0, 0.f), fmaxf(acc[n4][rg][1] + bv1, 0.f), 0, false);
                    d0 = (unsigned)__builtin_amdgcn_cvt_pk_fp8_f32(
                        fmaxf(acc[n4][rg][2] + bv2, 0.f), fmaxf(acc[n4][rg][3] + bv3, 0.f), (int)d0, true);
                    *(unsigned*)(hs + ((rg * 16 + l15) * 16 + u) * 8 + (g & 1) * 4) = d0;
                }
            }
        }

        // A2 fragments (fp8, swizzled) from dedicated Hs
        long a2[2][4];
#pragma unroll
        for (int rg = 0; rg < 2; ++rg)
#pragma unroll
            for (int kk = 0; kk < 4; ++kk)
                a2[rg][kk] = *(const long*)(hs + ((rg * 16 + l15) * 16 + ((kk * 4 + g) ^ rx)) * 8);

        // GEMM2 (fp8) + fused epilogue dot (overlaps in-flight staging)
        float rq[2][4] = {{0.f,0.f,0.f,0.f},{0.f,0.f,0.f,0.f}};
#pragma unroll
        for (int n = 0; n < 8; ++n) {
            f32x4 acc2[2] = {(f32x4){0.f,0.f,0.f,0.f}, (f32x4){0.f,0.f,0.f,0.f}};
            const unsigned char* wrow = sW1f + (n * 16 + l15) * 128;
#pragma unroll
            for (int kk = 0; kk < 4; ++kk) {
                long bb = *(const long*)(wrow + ((kk * 4 + g) ^ rx) * 8);
                acc2[0] = mfma_fp8(a2[0][kk], bb, acc2[0]);
                acc2[1] = mfma_fp8(a2[1][kk], bb, acc2[1]);
            }
            const float b1v = sB1W2[n * 16 + l15], w2v = sB1W2[128 + n * 16 + l15];
#pragma unroll
            for (int rg = 0; rg < 2; ++rg)
#pragma unroll
                for (int q = 0; q < 4; ++q)
                    rq[rg][q] += fmaxf(acc2[rg][q] + b1v, 0.f) * w2v;
        }

        // reduce over l15, store raw (2 float4) + per-lane mcode (1 dword)
#pragma unroll
        for (int off = 1; off < 16; off <<= 1)
#pragma unroll
            for (int rg = 0; rg < 2; ++rg)
#pragma unroll
                for (int q = 0; q < 4; ++q)
                    rq[rg][q] += __shfl_xor(rq[rg][q], off, 64);
        if (l15 == 0) {
#pragma unroll
            for (int rg = 0; rg < 2; ++rg) {
                const size_t m0 = rowb + rg * 16 + g * 4;
                *(float4*)(rawOut + m0) = make_float4(rq[rg][0] + b2v, rq[rg][1] + b2v,
                                                      rq[rg][2] + b2v, rq[rg][3] + b2v);
            }
        }
        if (l < 32) {
            const unsigned pmcu = ((unsigned)((int)mt.x + 1) << 1) | (mt.y > 0.f ? 1u : 0u);
            mcodeOut[rowb + l] = pmcu;
        }
        mt = mtN;
    }
}

// ---- kernel 2: fused per-batch-row stats + bias MLP + fair writeout ---------
__global__ __launch_bounds__(256) void k_bstats(
        const float* __restrict__ raw, const unsigned* __restrict__ mcode,
        const float* __restrict__ Wb0, const float* __restrict__ bb0,
        const float* __restrict__ Wb1, const float* __restrict__ bb1,
        float* __restrict__ out) {
    __shared__ unsigned scnt[512];
    __shared__ float    ssum[512];
    __shared__ unsigned smx[512];
    __shared__ float4   sstat[512];
    const int b = blockIdx.x, t = threadIdx.x;
    scnt[t] = 0u; ssum[t] = 0.f; smx[t] = 0u;
    scnt[t + 256] = 0u; ssum[t + 256] = 0.f; smx[t + 256] = 0u;
    __syncthreads();
    const int base = b * NC;
#pragma unroll 4
    for (int it = 0; it < 16; ++it) {
        int m = base + it * 256 + t;
        unsigned c = mcode[m];
        if ((c & 1u) && (c >> 1)) {
            int s = (int)(c >> 1) - 1;
            float r = raw[m];
            atomicAdd(&scnt[s], 1u);
            atomicAdd(&ssum[s], r);
            atomicMax(&smx[s], encf(r));
        }
    }
    __syncthreads();
#pragma unroll
    for (int k = 0; k < 2; ++k) {
        int s = t + k * 256;
        unsigned c = scnt[s];
        float smax = (c > 0) ? decf(smx[s]) : 0.f;
        float mean = ssum[s] / fmaxf((float)c, 1.f);
        float multi = (c > 1) ? 1.f : 0.f;
        float bias = 0.f;
        if (c > 1) {
            bias = bb1[0];
#pragma unroll
            for (int j = 0; j < 32; ++j) {
                float h = smax * Wb0[j] + mean * Wb0[32 + j] + (float)c * Wb0[64 + j] + bb0[j];
                bias += fmaxf(h, 0.f) * Wb1[j];
            }
        }
        sstat[s] = make_float4(smax, mean, bias, multi);
    }
    __syncthreads();
    const float4* raw4 = (const float4*)raw;
    const uint4*  mc4  = (const uint4*)mcode;
#pragma unroll
    for (int it = 0; it < 4; ++it) {
        int i = b * 1024 + it * 256 + t;
        float4 rv = raw4[i];
        uint4 mc = mc4[i];
        const float r[4]    = {rv.x, rv.y, rv.z, rv.w};
        const unsigned m[4] = {mc.x, mc.y, mc.z, mc.w};
        float fair[4], msk[4];
#pragma unroll
        for (int j = 0; j < 4; ++j) {
            msk[j] = (m[j] & 1u) ? 1.0f : 0.0f;
            float f;
            if (m[j] & 1u) {
                f = r[j];
                if (m[j] >> 1) {
                    float4 st = sstat[(int)(m[j] >> 1) - 1];
                    if (st.w > 0.5f) f = 1.5f * r[j] - st.y + 0.5f * st.x + st.z;
                }
            } else {
                f = NEGV;
            }
            fair[j] = f;
        }
        const size_t m0 = (size_t)i * 4;
        *(float4*)(out + m0) = make_float4(fair[0], fair[1], fair[2], fair[3]);
        *(float4*)(out + NELEM + m0) = make_float4(msk[0], msk[1], msk[2], msk[3]);
    }
}

// ---- launch ----------------------------------------------------------------
extern "C" void kernel_launch(void* const* d_in, const int* in_sizes, int n_in,
                              void* d_out, int out_size, void* d_ws, size_t ws_size,
                              hipStream_t stream) {
    const float* X   = (const float*)d_in[0];
    const float* W0  = (const float*)d_in[1];
    const float* b0  = (const float*)d_in[2];
    const float* W1  = (const float*)d_in[3];
    const float* b1  = (const float*)d_in[4];
    const float* W2  = (const float*)d_in[5];
    const float* b2  = (const float*)d_in[6];
    const float* Wb0 = (const float*)d_in[7];
    const float* bb0 = (const float*)d_in[8];
    const float* Wb1 = (const float*)d_in[9];
    const float* bb1 = (const float*)d_in[10];

    char* ws = (char*)d_ws;
    float*          raw      = (float*)(ws + 0);                 // 4 MB
    unsigned*       mcode    = (unsigned*)(ws + 4194304);        // 4 MB
    unsigned short* W0T      = (unsigned short*)(ws + 8388608);  // 16 KB
    unsigned char*  W1f8s    = (unsigned char*)(ws + 8404992);   // 16 KB

    k_prep<<<96, 256, 0, stream>>>(W0, W1, W0T, W1f8s);
    k_mlp<<<GRID_MLP, 256, 0, stream>>>(X, W0T, W1f8s, b0, b1, W2, b2, raw, mcode);
    k_bstats<<<NB, 256, 0, stream>>>(raw, mcode, Wb0, bb0, Wb1, bb1, (float*)d_out);
}